// Round 3
// baseline (7467.865 us; speedup 1.0000x reference)
//
#include <hip/hip_runtime.h>
#include <hip/hip_bf16.h>
#include <stdint.h>

// Problem constants
#define S_INPUT  1024
#define S_HIDDEN 2048
#define S_SEQ    256
#define S_BATCH  256
#define NWG_P    192    // persistent grid: 128 A-task + 64 B-task WGs

typedef __attribute__((ext_vector_type(8))) short bf16x8;   // 8 bf16 = 4 VGPRs
typedef __attribute__((ext_vector_type(4))) float f32x4;    // MFMA accumulator

__device__ __forceinline__ short f2bf(float f){
  union { float f; unsigned u; } v; v.f = f;
  unsigned r = v.u + 0x7fffu + ((v.u >> 16) & 1u);   // round-nearest-even
  return (short)(r >> 16);
}

// tanh via one v_exp_f32 + v_rcp_f32; exact at saturation.
__device__ __forceinline__ float tanh_fast(float x){
  float e = __expf(2.0f * x);
  return 1.0f - 2.0f / (e + 1.0f);
}

// ---------------------------------------------------------------------------
// Sense-reversing grid barrier. bar[0]=arrive count, bar[32]=generation
// (separate cachelines). Agent-scope release on arrive makes each WG's h/out
// stores visible device-wide (buffer_wbl2); the trailing acquire invalidates
// the reader's L1/L2 so next step's h loads are fresh (cross-XCD coherence).
// Relaxed spin + s_sleep, one acquire at exit (avoids per-poll L2 inval).
// ---------------------------------------------------------------------------
__device__ __forceinline__ void grid_sync(unsigned* bar, unsigned nwg)
{
  __syncthreads();   // drains each wave's vmcnt/lgkmcnt (stores retired)
  if (threadIdx.x == 0){
    unsigned* cnt = bar;
    unsigned* gen = bar + 32;
    unsigned g = __hip_atomic_load(gen, __ATOMIC_RELAXED, __HIP_MEMORY_SCOPE_AGENT);
    unsigned old = __hip_atomic_fetch_add(cnt, 1u, __ATOMIC_ACQ_REL, __HIP_MEMORY_SCOPE_AGENT);
    if (old == nwg - 1u){
      __hip_atomic_store(cnt, 0u, __ATOMIC_RELAXED, __HIP_MEMORY_SCOPE_AGENT);
      __hip_atomic_store(gen, g + 1u, __ATOMIC_RELEASE, __HIP_MEMORY_SCOPE_AGENT);
    } else {
      while (__hip_atomic_load(gen, __ATOMIC_RELAXED, __HIP_MEMORY_SCOPE_AGENT) == g)
        __builtin_amdgcn_s_sleep(1);
      (void)__hip_atomic_load(gen, __ATOMIC_ACQUIRE, __HIP_MEMORY_SCOPE_AGENT);
    }
  }
  __syncthreads();
}

// ---------------------------------------------------------------------------
// 64x64x(K) bf16 GEMM core, B^T layout: out[m][n] = sum_k A[m][k]*B[n][k].
// 4 waves in 2x2 grid; 4-deep LDS pipeline with counted vmcnt (validated R1).
// ---------------------------------------------------------------------------
__device__ __forceinline__ void compute_tile(const char* as, const char* bs,
                                             int ra0, int ra1, int rb0, int rb1,
                                             int hi, f32x4 acc[2][2])
{
  #pragma unroll
  for (int kk = 0; kk < 2; ++kk){
    const int kb = kk*64 + hi*16;
    bf16x8 a0 = *(const bf16x8*)(as + ra0*128 + (kb ^ ((ra0 & 7) << 4)));
    bf16x8 a1 = *(const bf16x8*)(as + ra1*128 + (kb ^ ((ra1 & 7) << 4)));
    bf16x8 b0 = *(const bf16x8*)(bs + rb0*128 + (kb ^ ((rb0 & 7) << 4)));
    bf16x8 b1 = *(const bf16x8*)(bs + rb1*128 + (kb ^ ((rb1 & 7) << 4)));
    acc[0][0] = __builtin_amdgcn_mfma_f32_16x16x32_bf16(a0, b0, acc[0][0], 0, 0, 0);
    acc[0][1] = __builtin_amdgcn_mfma_f32_16x16x32_bf16(a0, b1, acc[0][1], 0, 0, 0);
    acc[1][0] = __builtin_amdgcn_mfma_f32_16x16x32_bf16(a1, b0, acc[1][0], 0, 0, 0);
    acc[1][1] = __builtin_amdgcn_mfma_f32_16x16x32_bf16(a1, b1, acc[1][1], 0, 0, 0);
  }
}

__device__ __forceinline__ void gemm_core(const short* __restrict__ A, int lda,
                                          const short* __restrict__ B, int ldb,
                                          int bm, int bn, int ktiles,
                                          f32x4 acc[2][2], char* As, char* Bs)
{
  const int tid  = threadIdx.x;
  const int lane = tid & 63;
  const int wid  = tid >> 6;
  const int wm   = (wid >> 1) & 1;
  const int wn   = wid & 1;
  const int r15  = lane & 15;
  const int hi   = lane >> 4;
  const int ra0 = wm*32 + r15,  ra1 = ra0 + 16;
  const int rb0 = wn*32 + r15,  rb1 = rb0 + 16;

  const int c0 = tid, c1 = tid + 256;
  const int r0 = c0 >> 3, r1 = c1 >> 3;
  const int e0 = ((((c0 & 7) << 4) ^ ((r0 & 7) << 4)) >> 1);  // inverse swizzle
  const int e1 = ((((c1 & 7) << 4) ^ ((r1 & 7) << 4)) >> 1);
  const short* pa0 = A + (size_t)(bm + r0)*lda + e0;
  const short* pa1 = A + (size_t)(bm + r1)*lda + e1;
  const short* pb0 = B + (size_t)(bn + r0)*ldb + e0;
  const short* pb1 = B + (size_t)(bn + r1)*ldb + e1;
  char* la0 = As + c0*16;  char* la1 = As + c1*16;
  char* lb0 = Bs + c0*16;  char* lb1 = Bs + c1*16;

  #define STAGE(kt, s) do { \
    const int _ko = (kt)*64; const int _so = (s)*8192; \
    __builtin_amdgcn_global_load_lds((const __attribute__((address_space(1))) void*)(pa0 + _ko), \
                                     (__attribute__((address_space(3))) void*)(la0 + _so), 16, 0, 0); \
    __builtin_amdgcn_global_load_lds((const __attribute__((address_space(1))) void*)(pb0 + _ko), \
                                     (__attribute__((address_space(3))) void*)(lb0 + _so), 16, 0, 0); \
    __builtin_amdgcn_global_load_lds((const __attribute__((address_space(1))) void*)(pa1 + _ko), \
                                     (__attribute__((address_space(3))) void*)(la1 + _so), 16, 0, 0); \
    __builtin_amdgcn_global_load_lds((const __attribute__((address_space(1))) void*)(pb1 + _ko), \
                                     (__attribute__((address_space(3))) void*)(lb1 + _so), 16, 0, 0); \
  } while (0)

  STAGE(0, 0);
  if (ktiles > 1) STAGE(1, 1);
  if (ktiles > 2) STAGE(2, 2);

  for (int t = 0; t < ktiles; ++t){
    const int rem = ktiles - 1 - t;
    if (rem >= 2)      asm volatile("s_waitcnt vmcnt(8)" ::: "memory");
    else if (rem == 1) asm volatile("s_waitcnt vmcnt(4)" ::: "memory");
    else               asm volatile("s_waitcnt vmcnt(0)" ::: "memory");
    asm volatile("s_barrier" ::: "memory");   // raw barrier: no vmcnt drain
    if (t + 3 < ktiles) STAGE(t + 3, (t + 3) & 3);
    const char* as = As + (t & 3)*8192;
    const char* bs = Bs + (t & 3)*8192;
    compute_tile(as, bs, ra0, ra1, rb0, rb1, hi, acc);
  }
  #undef STAGE
}

// C/D layout (m89-verified): col = lane&15, row = (lane>>4)*4 + i.
#define EPI_COORDS \
  const int lane = threadIdx.x & 63, wid = threadIdx.x >> 6; \
  const int wm = (wid>>1)&1, wn = wid&1, r15 = lane&15, hi = lane>>4;

// ---------------------------------------------------------------------------
// Prologue kernels
// ---------------------------------------------------------------------------
__global__ __launch_bounds__(256) void k_build_wcat(const float* __restrict__ Wih,
                                                    const float* __restrict__ Whh,
                                                    short* __restrict__ Wcat)
{
  int j = blockIdx.x;
  for (int i = threadIdx.x; i < 3072; i += 256){
    float f = (i < 1024) ? Wih[(size_t)j*1024 + i] : Whh[(size_t)j*2048 + (i-1024)];
    Wcat[(size_t)j*3072 + i] = f2bf(f);
  }
}

__global__ __launch_bounds__(256) void k_build_acat(const float* __restrict__ x,
                                                    const float* __restrict__ h0,
                                                    short* __restrict__ Acat)
{
  int b = blockIdx.x;
  for (int i = threadIdx.x; i < 3072; i += 256){
    float f = (i < 1024) ? x[(size_t)b*1024 + i] : h0[(size_t)b*2048 + (i-1024)];
    Acat[(size_t)b*3072 + i] = f2bf(f);
  }
}

__global__ __launch_bounds__(256) void k_trans_wfc(const float* __restrict__ Wfc,
                                                   short* __restrict__ Wfcb,
                                                   short* __restrict__ WfcT)
{
  __shared__ float t[32][33];
  int i0 = blockIdx.x*32, k0 = blockIdx.y*32;
  int c = threadIdx.x & 31, r = threadIdx.x >> 5;
  #pragma unroll
  for (int rr = 0; rr < 4; ++rr){
    int i = i0 + r*4 + rr, k = k0 + c;
    float v = Wfc[(size_t)i*2048 + k];
    Wfcb[(size_t)i*2048 + k] = f2bf(v);
    t[r*4+rr][c] = v;
  }
  __syncthreads();
  #pragma unroll
  for (int rr = 0; rr < 4; ++rr){
    int k = k0 + r*4 + rr, i = i0 + c;
    WfcT[(size_t)k*1024 + i] = f2bf(t[c][r*4+rr]);
  }
}

__global__ __launch_bounds__(256) void k_cvec(const float* __restrict__ Wih,
                                              const float* __restrict__ bfc,
                                              const float* __restrict__ bih,
                                              const float* __restrict__ bhh,
                                              float* __restrict__ brnn,
                                              float* __restrict__ cvec)
{
  __shared__ float red[256];
  int j = blockIdx.x;
  float s = 0.f;
  for (int i = threadIdx.x; i < 1024; i += 256) s += Wih[(size_t)j*1024 + i]*bfc[i];
  red[threadIdx.x] = s; __syncthreads();
  for (int st = 128; st > 0; st >>= 1){
    if (threadIdx.x < st) red[threadIdx.x] += red[threadIdx.x+st];
    __syncthreads();
  }
  if (threadIdx.x == 0){
    float br = bih[j] + bhh[j];
    brnn[j] = br;
    cvec[j] = br + red[0];
  }
}

// Wcomb[j][k] = bf16( sum_i W_ih[j][i]*W_fc[i][k] + W_hh[j][k] )
__global__ __launch_bounds__(256) void k_wcomb(const short* __restrict__ Wcat,
                                               const short* __restrict__ WfcT,
                                               const float* __restrict__ Whh,
                                               short* __restrict__ Wcomb)
{
  __shared__ char As[4*8192], Bs[4*8192];
  f32x4 acc[2][2] = {};
  int bid = blockIdx.x;
  int xcd = bid & 7, j = bid >> 3;
  int np = xcd*4 + (j & 3);
  int mp = j >> 2;
  int bm = mp*64, bn = np*64;
  gemm_core(Wcat, 3072, WfcT, 1024, bm, bn, 16, acc, As, Bs);
  EPI_COORDS
  #pragma unroll
  for (int mi = 0; mi < 2; ++mi)
    #pragma unroll
    for (int ni = 0; ni < 2; ++ni){
      int n = bn + wn*32 + ni*16 + r15;
      #pragma unroll
      for (int i = 0; i < 4; ++i){
        int m = bm + wm*32 + mi*16 + hi*4 + i;
        Wcomb[(size_t)m*2048 + n] = f2bf(acc[mi][ni][i] + Whh[(size_t)m*2048 + n]);
      }
    }
}

// ---------------------------------------------------------------------------
// Persistent step kernel: one launch, 256 recurrence steps + out projections.
// Blocks 0..127 (A): h_{t+1} = tanh(h_t @ Wcomb^T + cvec)
// Blocks 128..191 (B): out_{t-1} = h_t @ Wfc^T + b_fc
// t=0 computes h1 from [x0|h0] (K=3072); post-loop B computes out_255.
// XCD-aware panel map: bid&7 = XCD -> each XCD re-reads only its own weight
// slice (1MB Wcomb + 0.5MB Wfc) per step.
// ---------------------------------------------------------------------------
__global__ __launch_bounds__(256) void k_persist(
    const short* __restrict__ Acat, const short* __restrict__ Wcat,
    const float* __restrict__ brnn,
    const short* __restrict__ Wcomb, const float* __restrict__ cvec,
    const short* __restrict__ Wfcb, const float* __restrict__ bfc,
    short* __restrict__ hb0, short* __restrict__ hb1,
    float* __restrict__ out, unsigned* __restrict__ bar)
{
  __shared__ char As[4*8192], Bs[4*8192];
  const int bid = blockIdx.x;

  // A-task panel coords (bid < 128)
  const int axcd = bid & 7, aj = bid >> 3;
  const int abm = (aj >> 2) * 64;
  const int abn = (axcd*4 + (aj & 3)) * 64;
  // B-task panel coords (bid >= 128)
  const int b2 = bid - 128;
  const int bxcd = b2 & 7, bj = b2 >> 3;
  const int bbm = (bj >> 1) * 64;
  const int bbn = (bxcd*2 + (bj & 1)) * 64;

  // ---- t = 0: h1 = tanh([x0|h0] @ [Wih|Whh]^T + brnn) ----
  if (bid < 128){
    f32x4 acc[2][2] = {};
    gemm_core(Acat, 3072, Wcat, 3072, abm, abn, 48, acc, As, Bs);
    EPI_COORDS
    #pragma unroll
    for (int mi = 0; mi < 2; ++mi)
      #pragma unroll
      for (int ni = 0; ni < 2; ++ni){
        int n = abn + wn*32 + ni*16 + r15;
        float cb = brnn[n];
        #pragma unroll
        for (int i = 0; i < 4; ++i){
          int m = abm + wm*32 + mi*16 + hi*4 + i;
          hb0[(size_t)m*S_HIDDEN + n] = f2bf(tanh_fast(acc[mi][ni][i] + cb));
        }
      }
  }
  grid_sync(bar, NWG_P);

  short* hc = hb0;   // h_t
  short* hn = hb1;   // h_{t+1}
  for (int t = 1; t <= 255; ++t){
    if (bid < 128){
      f32x4 acc[2][2] = {};
      gemm_core(hc, S_HIDDEN, Wcomb, S_HIDDEN, abm, abn, 32, acc, As, Bs);
      EPI_COORDS
      #pragma unroll
      for (int mi = 0; mi < 2; ++mi)
        #pragma unroll
        for (int ni = 0; ni < 2; ++ni){
          int n = abn + wn*32 + ni*16 + r15;
          float cb = cvec[n];
          #pragma unroll
          for (int i = 0; i < 4; ++i){
            int m = abm + wm*32 + mi*16 + hi*4 + i;
            hn[(size_t)m*S_HIDDEN + n] = f2bf(tanh_fast(acc[mi][ni][i] + cb));
          }
        }
    } else {
      f32x4 acc[2][2] = {};
      gemm_core(hc, S_HIDDEN, Wfcb, S_HIDDEN, bbm, bbn, 32, acc, As, Bs);
      float* outp = out + (size_t)(t-1)*S_INPUT;
      EPI_COORDS
      #pragma unroll
      for (int mi = 0; mi < 2; ++mi)
        #pragma unroll
        for (int ni = 0; ni < 2; ++ni){
          int n = bbn + wn*32 + ni*16 + r15;
          float cb = bfc[n];
          #pragma unroll
          for (int i = 0; i < 4; ++i){
            int m = bbm + wm*32 + mi*16 + hi*4 + i;
            outp[(size_t)m*(S_SEQ*S_INPUT) + n] = acc[mi][ni][i] + cb;
          }
        }
    }
    grid_sync(bar, NWG_P);
    short* tmp = hc; hc = hn; hn = tmp;
  }

  // ---- t = 256: out_255 = h_256 @ Wfc^T + b_fc (B-WGs only) ----
  if (bid >= 128){
    f32x4 acc[2][2] = {};
    gemm_core(hc, S_HIDDEN, Wfcb, S_HIDDEN, bbm, bbn, 32, acc, As, Bs);
    float* outp = out + (size_t)255*S_INPUT;
    EPI_COORDS
    #pragma unroll
    for (int mi = 0; mi < 2; ++mi)
      #pragma unroll
      for (int ni = 0; ni < 2; ++ni){
        int n = bbn + wn*32 + ni*16 + r15;
        float cb = bfc[n];
        #pragma unroll
        for (int i = 0; i < 4; ++i){
          int m = bbm + wm*32 + mi*16 + hi*4 + i;
          outp[(size_t)m*(S_SEQ*S_INPUT) + n] = acc[mi][ni][i] + cb;
        }
      }
  }
}

// ---------------------------------------------------------------------------
extern "C" void kernel_launch(void* const* d_in, const int* in_sizes, int n_in,
                              void* d_out, int out_size, void* d_ws, size_t ws_size,
                              hipStream_t stream)
{
  const float* x   = (const float*)d_in[0];   // (256,1,1024)
  const float* h0  = (const float*)d_in[1];   // (1,256,2048)
  const float* Wih = (const float*)d_in[2];   // (2048,1024)
  const float* Whh = (const float*)d_in[3];   // (2048,2048)
  const float* bih = (const float*)d_in[4];   // (2048)
  const float* bhh = (const float*)d_in[5];   // (2048)
  const float* Wfc = (const float*)d_in[6];   // (1024,2048)
  const float* bfc = (const float*)d_in[7];   // (1024)
  float* out = (float*)d_out;                 // (256,256,1024) f32

  char* ws = (char*)d_ws;
  size_t off = 0;
  auto alloc = [&](size_t bytes) -> void* {
    void* p = ws + off;
    off += (bytes + 255) & ~(size_t)255;
    return p;
  };
  short* Wcat = (short*)alloc((size_t)2048*3072*2);   // [W_ih | W_hh] bf16
  short* Acat = (short*)alloc((size_t)256*3072*2);    // [x0 | h0] bf16
  short* WfcT = (short*)alloc((size_t)2048*1024*2);   // W_fc^T bf16
  short* Wfcb = (short*)alloc((size_t)1024*2048*2);   // W_fc bf16
  short* Wcb  = (short*)alloc((size_t)2048*2048*2);   // Wcomb bf16
  short* hb0  = (short*)alloc((size_t)256*2048*2);
  short* hb1  = (short*)alloc((size_t)256*2048*2);
  float* brnn = (float*)alloc(2048*4);
  float* cvec = (float*)alloc(2048*4);
  unsigned* bar = (unsigned*)alloc(256);
  (void)ws_size; (void)in_sizes; (void)n_in; (void)out_size;

  // Zero the barrier (deterministic per launch; harness doesn't re-poison ws)
  hipMemsetAsync(bar, 0, 256, stream);

  // Prologue
  k_build_wcat<<<2048, 256, 0, stream>>>(Wih, Whh, Wcat);
  k_build_acat<<<256, 256, 0, stream>>>(x, h0, Acat);
  k_trans_wfc<<<dim3(32, 64), 256, 0, stream>>>(Wfc, Wfcb, WfcT);
  k_cvec<<<2048, 256, 0, stream>>>(Wih, bfc, bih, bhh, brnn, cvec);
  k_wcomb<<<1024, 256, 0, stream>>>(Wcat, WfcT, Whh, Wcb);

  // One persistent cooperative kernel for all 256 steps
  void* args[] = { (void*)&Acat, (void*)&Wcat, (void*)&brnn,
                   (void*)&Wcb,  (void*)&cvec,
                   (void*)&Wfcb, (void*)&bfc,
                   (void*)&hb0,  (void*)&hb1,
                   (void*)&out,  (void*)&bar };
  hipLaunchCooperativeKernel((const void*)k_persist, dim3(NWG_P), dim3(256),
                             args, 0, stream);
}